// Round 1
// baseline (302.969 us; speedup 1.0000x reference)
//
#include <hip/hip_runtime.h>

#define BLOCK 256

// ---------------------------------------------------------------------------
// ws layout: [0..3] nsat counter, [4..7] done ticket, [64 ..) sat byte array
// (padded to 16B multiple). All zeroed by zero_ws each call (ws is re-poisoned
// to 0xAA before every timed launch).
// ---------------------------------------------------------------------------

__global__ void zero_ws(uint4* __restrict__ ws, const int* __restrict__ n_clauses_p) {
    const int nc = *n_clauses_p;
    const int total16 = (64 + ((nc + 15) & ~15)) >> 4;  // uint4 count incl. header
    const uint4 z = {0u, 0u, 0u, 0u};
    int i = blockIdx.x * blockDim.x + threadIdx.x;
    const int stride = gridDim.x * blockDim.x;
    for (; i < total16; i += stride) ws[i] = z;
}

__device__ __forceinline__ void edge_one(int lit, int cls, int nv,
                                         const float* __restrict__ preds,
                                         unsigned char* __restrict__ sat) {
    const bool pos = lit < nv;
    const int v = pos ? lit : lit - nv;
    const float p = preds[v];
    // pos ? (p >= 0.5) : (p < 0.5)  ==  pos == (p >= 0.5)   (no NaNs in uniform)
    if (pos == (p >= 0.5f)) sat[cls] = (unsigned char)1;
}

__global__ void scatter_sat(const int* __restrict__ lits,
                            const int* __restrict__ clauses,
                            const float* __restrict__ preds,
                            unsigned char* __restrict__ sat,
                            int n_edges,
                            const int* __restrict__ n_vars_p) {
    const int nv = *n_vars_p;
    const int tid = blockIdx.x * blockDim.x + threadIdx.x;
    const int stride = gridDim.x * blockDim.x;
    const int n4 = n_edges >> 2;

    const int4* __restrict__ l4 = reinterpret_cast<const int4*>(lits);
    const int4* __restrict__ c4 = reinterpret_cast<const int4*>(clauses);

    for (int i = tid; i < n4; i += stride) {
        const int4 l = l4[i];
        const int4 c = c4[i];
        edge_one(l.x, c.x, nv, preds, sat);
        edge_one(l.y, c.y, nv, preds, sat);
        edge_one(l.z, c.z, nv, preds, sat);
        edge_one(l.w, c.w, nv, preds, sat);
    }
    // tail (n_edges not multiple of 4)
    for (int i = (n4 << 2) + tid; i < n_edges; i += stride) {
        edge_one(lits[i], clauses[i], nv, preds, sat);
    }
}

__global__ void reduce_finalize(const uint4* __restrict__ sat16,
                                unsigned* __restrict__ nsat,
                                unsigned* __restrict__ done,
                                float* __restrict__ out,
                                const int* __restrict__ n_clauses_p,
                                const int* __restrict__ n_vars_p) {
    const int nc = *n_clauses_p;
    const int n16 = (nc + 15) >> 4;   // bytes beyond nc are zeroed, safe to read
    const int tid = blockIdx.x * blockDim.x + threadIdx.x;
    const int stride = gridDim.x * blockDim.x;

    unsigned acc = 0;
    for (int i = tid; i < n16; i += stride) {
        const uint4 v = sat16[i];
        acc += __popc(v.x & 0x01010101u) + __popc(v.y & 0x01010101u) +
               __popc(v.z & 0x01010101u) + __popc(v.w & 0x01010101u);
    }

    // wave (64-lane) reduce
    #pragma unroll
    for (int off = 32; off > 0; off >>= 1) acc += __shfl_down(acc, off);

    __shared__ unsigned smem[BLOCK / 64];
    const int lane = threadIdx.x & 63;
    const int wid  = threadIdx.x >> 6;
    if (lane == 0) smem[wid] = acc;
    __syncthreads();

    if (threadIdx.x == 0) {
        unsigned bsum = 0;
        #pragma unroll
        for (int w = 0; w < BLOCK / 64; ++w) bsum += smem[w];
        atomicAdd(nsat, bsum);
        __threadfence();                       // make my add visible before ticket
        const unsigned ticket = atomicAdd(done, 1u);
        if (ticket == (unsigned)(gridDim.x - 1)) {
            const unsigned total = atomicAdd(nsat, 0u);   // coherent read
            const float nv = (float)(*n_vars_p);
            *out = ((float)nc - (float)total) / nv;
        }
    }
}

extern "C" void kernel_launch(void* const* d_in, const int* in_sizes, int n_in,
                              void* d_out, int out_size, void* d_ws, size_t ws_size,
                              hipStream_t stream) {
    const float* preds   = (const float*)d_in[0];
    const int*   lits    = (const int*)d_in[1];
    const int*   clauses = (const int*)d_in[2];
    const int*   nv_p    = (const int*)d_in[3];   // 1-element device scalar
    const int*   nc_p    = (const int*)d_in[4];   // 1-element device scalar
    const int    n_edges = in_sizes[1];

    float* out = (float*)d_out;
    unsigned char* ws = (unsigned char*)d_ws;
    unsigned* nsat = (unsigned*)ws;
    unsigned* done = (unsigned*)(ws + 4);
    unsigned char* sat = ws + 64;

    zero_ws<<<1024, BLOCK, 0, stream>>>((uint4*)ws, nc_p);
    scatter_sat<<<2048, BLOCK, 0, stream>>>(lits, clauses, preds, sat, n_edges, nv_p);
    reduce_finalize<<<512, BLOCK, 0, stream>>>((const uint4*)sat, nsat, done, out,
                                               nc_p, nv_p);
}